// Round 1
// baseline (470.937 us; speedup 1.0000x reference)
//
#include <hip/hip_runtime.h>

typedef __bf16 bf16x8 __attribute__((ext_vector_type(8)));
typedef float f32x4 __attribute__((ext_vector_type(4)));

// ---- workspace layout (bf16 element offsets) ----
#define W0T_OFF 0                   // [512][32]  (k padded 16->32 with zeros)
#define W1T_OFF 16384               // [512][512]
#define W2T_OFF (16384 + 262144)    // [160][512] (n padded 136->160 with zeros)
#define PREP_TOTAL (16384 + 262144 + 81920)

__global__ void prep_weights(const float* __restrict__ W0,
                             const float* __restrict__ W1,
                             const float* __restrict__ W2,
                             __bf16* __restrict__ ws) {
    int t = blockIdx.x * 256 + threadIdx.x;
    if (t < 16384) {
        int n = t >> 5, k = t & 31;
        ws[W0T_OFF + t] = (k < 16) ? (__bf16)W0[k * 512 + n] : (__bf16)0.0f;
    } else if (t < 16384 + 262144) {
        int u = t - 16384;
        int n = u >> 9, k = u & 511;
        ws[W1T_OFF + u] = (__bf16)W1[k * 512 + n];
    } else if (t < PREP_TOTAL) {
        int u = t - (16384 + 262144);
        int n = u >> 9, k = u & 511;
        ws[W2T_OFF + u] = (n < 136) ? (__bf16)W2[k * 136 + n] : (__bf16)0.0f;
    }
}

__device__ __forceinline__ float fast_tanh(float x) {
    // tanh(x) = 1 - 2/(exp2(2*log2e*x)+1); exp2->inf/0 gives correct +-1 saturation
#if __has_builtin(__builtin_amdgcn_exp2f)
    float e = __builtin_amdgcn_exp2f(x * 2.885390081777926f);
#else
    float e = exp2f(x * 2.885390081777926f);
#endif
    return 1.0f - 2.0f * __builtin_amdgcn_rcpf(e + 1.0f);
}

// h LDS layout: row m (32 rows), 512 bf16/row, 16B k-blocks XOR-swizzled by m&7
// -> conflict-free ds_read_b128 a-fragment reads (8 bank-groups x2 lanes = free)
__device__ __forceinline__ int h_idx(int m, int k) {
    return m * 512 + ((((k >> 3) ^ (m & 7)) << 3)) + (k & 7);
}

__global__ __launch_bounds__(256, 2)
void fused_mlp_quad(const float* __restrict__ points,
                    const float* __restrict__ b0,
                    const float* __restrict__ b1,
                    const float* __restrict__ b2,
                    const __bf16* __restrict__ ws,
                    float* __restrict__ out) {
    __shared__ __align__(16) unsigned char lds_raw[65536];
    __bf16* h0 = (__bf16*)lds_raw;               // [32][512] swizzled bf16
    __bf16* h1 = (__bf16*)(lds_raw + 32768);     // [32][512] swizzled bf16
    float*  net = (float*)lds_raw;               // [32][137] fp32, reuses h0 region

    const __bf16* w0t = ws + W0T_OFF;
    const __bf16* w1t = ws + W1T_OFF;
    const __bf16* w2t = ws + W2T_OFF;

    const int tid = threadIdx.x;
    const int w   = tid >> 6;    // wave 0..3
    const int l   = tid & 63;
    const int c   = l & 15;      // MFMA lane col
    const int q   = l >> 4;      // quad
    const int row0 = blockIdx.x * 32;

    // ---------- phase 0: h0 = tanh(x @ W0 + b0) ----------
    // A-operand (x) fragments, K=16 padded to 32 (quads 2,3 zero)
    bf16x8 ax[2];
#pragma unroll
    for (int mt = 0; mt < 2; ++mt) {
        bf16x8 a;
#pragma unroll
        for (int j = 0; j < 8; ++j) a[j] = (__bf16)0.0f;
        if (q < 2) {
            const float* src = points + (row0 + mt * 16 + c) * 16 + q * 8;
            float4 p0 = ((const float4*)src)[0];
            float4 p1 = ((const float4*)src)[1];
            a[0] = (__bf16)p0.x; a[1] = (__bf16)p0.y;
            a[2] = (__bf16)p0.z; a[3] = (__bf16)p0.w;
            a[4] = (__bf16)p1.x; a[5] = (__bf16)p1.y;
            a[6] = (__bf16)p1.z; a[7] = (__bf16)p1.w;
        }
        ax[mt] = a;
    }
#pragma unroll
    for (int t = 0; t < 8; ++t) {
        const int n = (w * 8 + t) * 16 + c;
        bf16x8 b = *(const bf16x8*)(w0t + n * 32 + q * 8);
        float bias = b0[n];
#pragma unroll
        for (int mt = 0; mt < 2; ++mt) {
            f32x4 acc = {0.f, 0.f, 0.f, 0.f};
            acc = __builtin_amdgcn_mfma_f32_16x16x32_bf16(ax[mt], b, acc, 0, 0, 0);
#pragma unroll
            for (int r = 0; r < 4; ++r) {
                int m = mt * 16 + q * 4 + r;
                h0[h_idx(m, n)] = (__bf16)fast_tanh(acc[r] + bias);
            }
        }
    }
    __syncthreads();

    // ---------- phase 1: h1 = tanh(h0 @ W1 + b1) ----------
    // per wave: 8 n-tiles x 2 m-tiles, K-loop 16 steps of 32
    f32x4 acc1[8][2] = {};
    for (int kk = 0; kk < 16; ++kk) {
        const int blk = (kk << 2) + q;
        bf16x8 a0 = *(const bf16x8*)(h0 + c * 512 + ((blk ^ (c & 7)) << 3));
        bf16x8 a1 = *(const bf16x8*)(h0 + (16 + c) * 512 + ((blk ^ (c & 7)) << 3));
#pragma unroll
        for (int t = 0; t < 8; ++t) {
            const int n = (w * 8 + t) * 16 + c;
            bf16x8 b = *(const bf16x8*)(w1t + n * 512 + kk * 32 + q * 8);
            acc1[t][0] = __builtin_amdgcn_mfma_f32_16x16x32_bf16(a0, b, acc1[t][0], 0, 0, 0);
            acc1[t][1] = __builtin_amdgcn_mfma_f32_16x16x32_bf16(a1, b, acc1[t][1], 0, 0, 0);
        }
    }
#pragma unroll
    for (int t = 0; t < 8; ++t) {
        const int n = (w * 8 + t) * 16 + c;
        float bias = b1[n];
#pragma unroll
        for (int mt = 0; mt < 2; ++mt) {
#pragma unroll
            for (int r = 0; r < 4; ++r) {
                int m = mt * 16 + q * 4 + r;
                h1[h_idx(m, n)] = (__bf16)fast_tanh(acc1[t][mt][r] + bias);
            }
        }
    }
    __syncthreads();

    // ---------- phase 2: net = h1 @ W2 + b2  (N padded to 160 -> 10 n-tiles) ----------
    // 20 (nt,mt) tiles over 4 waves = 5 tiles/wave
    f32x4 acc2[5] = {};
    for (int kk = 0; kk < 16; ++kk) {
        const int blk = (kk << 2) + q;
        bf16x8 a0 = *(const bf16x8*)(h1 + c * 512 + ((blk ^ (c & 7)) << 3));
        bf16x8 a1 = *(const bf16x8*)(h1 + (16 + c) * 512 + ((blk ^ (c & 7)) << 3));
#pragma unroll
        for (int i = 0; i < 5; ++i) {
            int flat = w * 5 + i;
            int n = (flat >> 1) * 16 + c;
            bf16x8 b = *(const bf16x8*)(w2t + n * 512 + kk * 32 + q * 8);
            acc2[i] = __builtin_amdgcn_mfma_f32_16x16x32_bf16((flat & 1) ? a1 : a0, b, acc2[i], 0, 0, 0);
        }
    }
    // write net (fp32) into LDS, rows stride 137 (odd -> conflict-spread)
#pragma unroll
    for (int i = 0; i < 5; ++i) {
        int flat = w * 5 + i;
        int n = (flat >> 1) * 16 + c;
        int mt = flat & 1;
        if (n < 136) {
            float bias = b2[n];
#pragma unroll
            for (int r = 0; r < 4; ++r) {
                int m = mt * 16 + q * 4 + r;
                net[m * 137 + n] = acc2[i][r] + bias;
            }
        }
    }
    __syncthreads();

    // ---------- phase 3: vals = ||M^T x||^2 + eps*||x||^2 ----------
    // 8 threads per row; thread jg handles cols j = jg, jg+8
    {
        const int r  = tid >> 3;
        const int jg = tid & 7;
        const float* xp = points + (row0 + r) * 16;
        float xv[16];
#pragma unroll
        for (int i = 0; i < 4; ++i) {
            float4 v = ((const float4*)xp)[i];
            xv[i * 4 + 0] = v.x; xv[i * 4 + 1] = v.y;
            xv[i * 4 + 2] = v.z; xv[i * 4 + 3] = v.w;
        }
        float sumsq = 0.f;
#pragma unroll
        for (int i = 0; i < 16; ++i) sumsq += xv[i] * xv[i];
        float p = 0.f;
#pragma unroll
        for (int jj = 0; jj < 2; ++jj) {
            const int j = jg + jj * 8;
            float y = 0.f;
#pragma unroll
            for (int i = 0; i < 16; ++i) {
                // tril index k = i(i+1)/2 + j, valid (in-bounds) even when i<j; predicated off
                float mv = net[r * 137 + ((i * (i + 1)) >> 1) + j];
                y += (i >= j) ? mv * xv[i] : 0.f;
            }
            p += y * y;
        }
        p += __shfl_xor(p, 1);
        p += __shfl_xor(p, 2);
        p += __shfl_xor(p, 4);
        if (jg == 0) out[row0 + r] = p + 1e-6f * sumsq;
    }
}

extern "C" void kernel_launch(void* const* d_in, const int* in_sizes, int n_in,
                              void* d_out, int out_size, void* d_ws, size_t ws_size,
                              hipStream_t stream) {
    const float* points = (const float*)d_in[0];
    const float* W0 = (const float*)d_in[1];
    const float* b0 = (const float*)d_in[2];
    const float* W1 = (const float*)d_in[3];
    const float* b1 = (const float*)d_in[4];
    const float* W2 = (const float*)d_in[5];
    const float* b2 = (const float*)d_in[6];
    __bf16* ws = (__bf16*)d_ws;
    float* out = (float*)d_out;

    prep_weights<<<(PREP_TOTAL + 255) / 256, 256, 0, stream>>>(W0, W1, W2, ws);

    const int B = in_sizes[0] / 16;   // 131072
    fused_mlp_quad<<<B / 32, 256, 0, stream>>>(points, b0, b1, b2, ws, out);
}

// Round 2
// 358.618 us; speedup vs baseline: 1.3132x; 1.3132x over previous
//
#include <hip/hip_runtime.h>

typedef __bf16 bf16x8 __attribute__((ext_vector_type(8)));
typedef float f32x4 __attribute__((ext_vector_type(4)));

// ---- workspace layout (bf16 element offsets) ----
#define W0T_OFF 0                   // [512][32]  (k padded 16->32 with zeros)
#define W1T_OFF 16384               // [512][512]
#define W2T_OFF (16384 + 262144)    // [144][512] (n padded 136->144 with zeros)
#define PREP_TOTAL (16384 + 262144 + 73728)

__global__ void prep_weights(const float* __restrict__ W0,
                             const float* __restrict__ W1,
                             const float* __restrict__ W2,
                             __bf16* __restrict__ ws) {
    int t = blockIdx.x * 256 + threadIdx.x;
    if (t < 16384) {
        int n = t >> 5, k = t & 31;
        ws[W0T_OFF + t] = (k < 16) ? (__bf16)W0[k * 512 + n] : (__bf16)0.0f;
    } else if (t < 16384 + 262144) {
        int u = t - 16384;
        int n = u >> 9, k = u & 511;
        ws[W1T_OFF + u] = (__bf16)W1[k * 512 + n];
    } else if (t < PREP_TOTAL) {
        int u = t - (16384 + 262144);
        int n = u >> 9, k = u & 511;
        ws[W2T_OFF + u] = (n < 136) ? (__bf16)W2[k * 136 + n] : (__bf16)0.0f;
    }
}

__device__ __forceinline__ float fast_tanh(float x) {
    // tanh(x) = 1 - 2/(exp2(2*log2e*x)+1); exp2->inf/0 gives correct +-1 saturation
#if __has_builtin(__builtin_amdgcn_exp2f)
    float e = __builtin_amdgcn_exp2f(x * 2.885390081777926f);
#else
    float e = exp2f(x * 2.885390081777926f);
#endif
    return 1.0f - 2.0f * __builtin_amdgcn_rcpf(e + 1.0f);
}

// h LDS layout: [64][512] bf16; 16B k-blocks XOR-swizzled by
// s(m) = ((m>>2)&3)<<1 ^ (m&7). Writes: the 4 quads (m = q*4+r) map to 4
// DISJOINT bank groups (2 lanes/bank = free); reads: s over m=0..15 covers
// each value exactly twice -> 2-way-equivalent b128 reads (free).
__device__ __forceinline__ int h_swz(int m) {
    return (((m >> 2) & 3) << 1) ^ (m & 7);
}
__device__ __forceinline__ int h_idx(int m, int k) {
    return m * 512 + (((k >> 3) ^ h_swz(m)) << 3) + (k & 7);
}

__global__ __launch_bounds__(256, 2)
void fused_mlp_quad(const float* __restrict__ points,
                    const float* __restrict__ b0,
                    const float* __restrict__ b1,
                    const float* __restrict__ b2,
                    const __bf16* __restrict__ ws,
                    float* __restrict__ out) {
    __shared__ __align__(16) unsigned char lds_raw[65536];
    __bf16* h  = (__bf16*)lds_raw;   // [64][512] swizzled bf16 (h0, then h1 in place)
    float* net = (float*)lds_raw;    // [64][137] fp32, overlays h after phase 2

    const __bf16* w0t = ws + W0T_OFF;
    const __bf16* w1t = ws + W1T_OFF;
    const __bf16* w2t = ws + W2T_OFF;

    const int tid = threadIdx.x;
    const int w   = tid >> 6;    // wave 0..3
    const int l   = tid & 63;
    const int c   = l & 15;      // MFMA lane col
    const int q   = l >> 4;      // quad
    const int row0 = blockIdx.x * 64;

    // ---------- phase 0: h0 = tanh(x @ W0 + b0) ----------
    bf16x8 ax[4];
#pragma unroll
    for (int mt = 0; mt < 4; ++mt) {
        bf16x8 a;
#pragma unroll
        for (int j = 0; j < 8; ++j) a[j] = (__bf16)0.0f;
        if (q < 2) {
            const float* src = points + (row0 + mt * 16 + c) * 16 + q * 8;
            float4 p0 = ((const float4*)src)[0];
            float4 p1 = ((const float4*)src)[1];
            a[0] = (__bf16)p0.x; a[1] = (__bf16)p0.y;
            a[2] = (__bf16)p0.z; a[3] = (__bf16)p0.w;
            a[4] = (__bf16)p1.x; a[5] = (__bf16)p1.y;
            a[6] = (__bf16)p1.z; a[7] = (__bf16)p1.w;
        }
        ax[mt] = a;
    }
#pragma unroll
    for (int t = 0; t < 8; ++t) {
        const int n = (w * 8 + t) * 16 + c;
        bf16x8 b = *(const bf16x8*)(w0t + n * 32 + q * 8);
        float bias = b0[n];
#pragma unroll
        for (int mt = 0; mt < 4; ++mt) {
            f32x4 acc = {0.f, 0.f, 0.f, 0.f};
            acc = __builtin_amdgcn_mfma_f32_16x16x32_bf16(ax[mt], b, acc, 0, 0, 0);
#pragma unroll
            for (int r = 0; r < 4; ++r) {
                int m = mt * 16 + q * 4 + r;
                h[h_idx(m, n)] = (__bf16)fast_tanh(acc[r] + bias);
            }
        }
    }
    __syncthreads();

    // ---------- phase 1: h1 = tanh(h0 @ W1 + b1), acc in regs, h1 in place ----------
    f32x4 acc1[8][4] = {};
    {
        // a-frag bases per m-tile (lane-constant swizzle)
        const __bf16* abase[4];
        int asw[4];
#pragma unroll
        for (int mt = 0; mt < 4; ++mt) {
            int m = mt * 16 + c;
            abase[mt] = h + m * 512;
            asw[mt] = h_swz(m);
        }
        const __bf16* bbase = w1t + (w * 128 + c) * 512 + q * 8;  // + t*16*512 + kk*32
        bf16x8 bb[2][8];
#pragma unroll
        for (int t = 0; t < 8; ++t)
            bb[0][t] = *(const bf16x8*)(bbase + t * 8192);
#pragma unroll 2
        for (int kk = 0; kk < 16; ++kk) {
            const int cur = kk & 1, nxt = cur ^ 1;
            const int kn = (kk + 1 < 16) ? (kk + 1) : 0;   // guard: don't read past w1t
#pragma unroll
            for (int t = 0; t < 8; ++t)
                bb[nxt][t] = *(const bf16x8*)(bbase + t * 8192 + kn * 32);
            const int blk = (kk << 2) + q;
            bf16x8 a[4];
#pragma unroll
            for (int mt = 0; mt < 4; ++mt)
                a[mt] = *(const bf16x8*)(abase[mt] + ((blk ^ asw[mt]) << 3));
#pragma unroll
            for (int t = 0; t < 8; ++t)
#pragma unroll
                for (int mt = 0; mt < 4; ++mt)
                    acc1[t][mt] = __builtin_amdgcn_mfma_f32_16x16x32_bf16(
                        a[mt], bb[cur][t], acc1[t][mt], 0, 0, 0);
        }
    }
    __syncthreads();   // all reads of h0 done; safe to overwrite
#pragma unroll
    for (int t = 0; t < 8; ++t) {
        const int n = (w * 8 + t) * 16 + c;
        float bias = b1[n];
#pragma unroll
        for (int mt = 0; mt < 4; ++mt) {
#pragma unroll
            for (int r = 0; r < 4; ++r) {
                int m = mt * 16 + q * 4 + r;
                h[h_idx(m, n)] = (__bf16)fast_tanh(acc1[t][mt][r] + bias);
            }
        }
    }
    __syncthreads();

    // ---------- phase 2: net = h1 @ W2 + b2  (N padded to 144 -> 9 n-tiles) ----------
    // 36 (nt,mt) tiles over 4 waves = 9/wave: (w,0..3), (w+4,0..3), (8,w)
    f32x4 acc2[9] = {};
    {
        const __bf16* abase[4];
        int asw[4];
#pragma unroll
        for (int mt = 0; mt < 4; ++mt) {
            int m = mt * 16 + c;
            abase[mt] = h + m * 512;
            asw[mt] = h_swz(m);
        }
        const int nt[3] = {w, w + 4, 8};
        bf16x8 cb[2][3];
#pragma unroll
        for (int j = 0; j < 3; ++j)
            cb[0][j] = *(const bf16x8*)(w2t + (nt[j] * 16 + c) * 512 + q * 8);
#pragma unroll 2
        for (int kk = 0; kk < 16; ++kk) {
            const int cur = kk & 1, nxt = cur ^ 1;
            const int kn = (kk + 1 < 16) ? (kk + 1) : 0;
#pragma unroll
            for (int j = 0; j < 3; ++j)
                cb[nxt][j] = *(const bf16x8*)(w2t + (nt[j] * 16 + c) * 512 + kn * 32 + q * 8);
            const int blk = (kk << 2) + q;
            bf16x8 a[4];
#pragma unroll
            for (int mt = 0; mt < 4; ++mt)
                a[mt] = *(const bf16x8*)(abase[mt] + ((blk ^ asw[mt]) << 3));
#pragma unroll
            for (int i = 0; i < 9; ++i) {
                const int bj = (i < 4) ? 0 : (i < 8) ? 1 : 2;
                const int mt = (i < 8) ? (i & 3) : w;
                acc2[i] = __builtin_amdgcn_mfma_f32_16x16x32_bf16(
                    a[mt], cb[cur][bj], acc2[i], 0, 0, 0);
            }
        }
    }
    __syncthreads();   // all reads of h1 done; overwrite with net (fp32)
#pragma unroll
    for (int i = 0; i < 9; ++i) {
        const int ntl = (i < 4) ? w : (i < 8) ? (w + 4) : 8;
        const int mt  = (i < 8) ? (i & 3) : w;
        const int n = ntl * 16 + c;
        if (n < 136) {
            float bias = b2[n];
#pragma unroll
            for (int r = 0; r < 4; ++r) {
                int m = mt * 16 + q * 4 + r;
                net[m * 137 + n] = acc2[i][r] + bias;
            }
        }
    }
    __syncthreads();

    // ---------- phase 3: vals = ||M^T x||^2 + eps*||x||^2 ----------
    // 8 threads per row; 32 rows per pass, 2 passes
#pragma unroll
    for (int half = 0; half < 2; ++half) {
        const int r  = half * 32 + (tid >> 3);
        const int jg = tid & 7;
        const float* xp = points + (row0 + r) * 16;
        float xv[16];
#pragma unroll
        for (int i = 0; i < 4; ++i) {
            float4 v = ((const float4*)xp)[i];
            xv[i * 4 + 0] = v.x; xv[i * 4 + 1] = v.y;
            xv[i * 4 + 2] = v.z; xv[i * 4 + 3] = v.w;
        }
        float sumsq = 0.f;
#pragma unroll
        for (int i = 0; i < 16; ++i) sumsq += xv[i] * xv[i];
        float p = 0.f;
#pragma unroll
        for (int jj = 0; jj < 2; ++jj) {
            const int j = jg + jj * 8;
            float y = 0.f;
#pragma unroll
            for (int i = 0; i < 16; ++i) {
                float mv = net[r * 137 + ((i * (i + 1)) >> 1) + j];
                y += (i >= j) ? mv * xv[i] : 0.f;
            }
            p += y * y;
        }
        p += __shfl_xor(p, 1);
        p += __shfl_xor(p, 2);
        p += __shfl_xor(p, 4);
        if (jg == 0) out[row0 + r] = p + 1e-6f * sumsq;
    }
}

extern "C" void kernel_launch(void* const* d_in, const int* in_sizes, int n_in,
                              void* d_out, int out_size, void* d_ws, size_t ws_size,
                              hipStream_t stream) {
    const float* points = (const float*)d_in[0];
    const float* W0 = (const float*)d_in[1];
    const float* b0 = (const float*)d_in[2];
    const float* W1 = (const float*)d_in[3];
    const float* b1 = (const float*)d_in[4];
    const float* W2 = (const float*)d_in[5];
    const float* b2 = (const float*)d_in[6];
    __bf16* ws = (__bf16*)d_ws;
    float* out = (float*)d_out;

    prep_weights<<<(PREP_TOTAL + 255) / 256, 256, 0, stream>>>(W0, W1, W2, ws);

    const int B = in_sizes[0] / 16;   // 131072
    fused_mlp_quad<<<B / 64, 256, 0, stream>>>(points, b0, b1, b2, ws, out);
}